// Round 1
// baseline (160.969 us; speedup 1.0000x reference)
//
#include <hip/hip_runtime.h>

#define NN 8192
#define NE 262144

// ---------- HW = feat @ W  (f32, VALU) ----------
// block 256 = 2x(128 f-threads), 16 rows/block, 8 rows per thread-half.
__global__ __launch_bounds__(256) void k_gemm(const float* __restrict__ feat,
                                              const float* __restrict__ Wm,
                                              float* __restrict__ HW) {
    __shared__ float fs[16 * 256];
    const int tid = threadIdx.x;
    const int f = tid & 127;
    const int rh = tid >> 7;
    const int row0 = blockIdx.x * 16;
    for (int idx = tid * 4; idx < 16 * 256; idx += 256 * 4) {
        *(float4*)&fs[idx] = *(const float4*)&feat[row0 * 256 + idx];
    }
    __syncthreads();
    float acc[8];
#pragma unroll
    for (int r = 0; r < 8; ++r) acc[r] = 0.f;
    const float* fsr = fs + rh * 8 * 256;
    for (int k = 0; k < 256; k += 4) {
        const float w0 = Wm[(k + 0) * 128 + f];
        const float w1 = Wm[(k + 1) * 128 + f];
        const float w2 = Wm[(k + 2) * 128 + f];
        const float w3 = Wm[(k + 3) * 128 + f];
#pragma unroll
        for (int r = 0; r < 8; ++r) {
            const float4 fv = *(const float4*)&fsr[r * 256 + k];
            acc[r] += fv.x * w0 + fv.y * w1 + fv.z * w2 + fv.w * w3;
        }
    }
#pragma unroll
    for (int r = 0; r < 8; ++r) {
        HW[(row0 + rh * 8 + r) * 128 + f] = acc[r];
    }
}

// ---------- s_i = HW_i . a[:128], t_i = HW_i . a[128:] ----------
__global__ __launch_bounds__(256) void k_st(const float* __restrict__ HW,
                                            const float* __restrict__ a,
                                            float* __restrict__ s,
                                            float* __restrict__ t) {
    const int lane = threadIdx.x & 63;
    const int row = blockIdx.x * 4 + (threadIdx.x >> 6);
    const float* h = HW + row * 128;
    const float v0 = h[lane], v1 = h[64 + lane];
    float su = v0 * a[lane] + v1 * a[64 + lane];
    float tu = v0 * a[128 + lane] + v1 * a[192 + lane];
    for (int off = 32; off; off >>= 1) {
        su += __shfl_xor(su, off);
        tu += __shfl_xor(tu, off);
    }
    if (lane == 0) { s[row] = su; t[row] = tu; }
}

// ---------- CSR build ----------
__global__ __launch_bounds__(256) void k_count(const int* __restrict__ src,
                                               int* __restrict__ cnt) {
    const int e = blockIdx.x * 256 + threadIdx.x;
    if (e < NE) atomicAdd(&cnt[src[e]], 1);
}

__global__ __launch_bounds__(1024) void k_scan(const int* __restrict__ cnt,
                                               int* __restrict__ row_start,
                                               int* __restrict__ cur_ofs) {
    __shared__ int part[1024];
    const int tid = threadIdx.x;
    int c[8];
    int sum = 0;
#pragma unroll
    for (int r = 0; r < 8; ++r) { c[r] = cnt[tid * 8 + r]; sum += c[r]; }
    part[tid] = sum;
    __syncthreads();
    for (int off = 1; off < 1024; off <<= 1) {
        int v = part[tid];
        if (tid >= off) v += part[tid - off];
        __syncthreads();
        part[tid] = v;
        __syncthreads();
    }
    int run = (tid == 0) ? 0 : part[tid - 1];
#pragma unroll
    for (int r = 0; r < 8; ++r) {
        const int row = tid * 8 + r;
        row_start[row] = run;
        cur_ofs[row] = run;
        run += c[r];
    }
    if (tid == 1023) row_start[NN] = part[1023];
}

__global__ __launch_bounds__(256) void k_scatter(const int* __restrict__ src,
                                                 const int* __restrict__ dst,
                                                 int* __restrict__ cur_ofs,
                                                 int* __restrict__ col) {
    const int e = blockIdx.x * 256 + threadIdx.x;
    if (e < NE) {
        const int i = src[e];
        const int pos = atomicAdd(&cur_ofs[i], 1);
        col[pos] = dst[e];
    }
}

// ---------- per-edge leakyrelu value, multiplicity, column-norm accumulation ----------
// norm2[j] = sum over distinct (i,j) of (c*lr)^2 == sum over instances of c*lr^2
__global__ __launch_bounds__(256) void k_dupnorm(const int* __restrict__ row_start,
                                                 const int* __restrict__ col,
                                                 const float* __restrict__ s,
                                                 const float* __restrict__ t,
                                                 float* __restrict__ lr_e,
                                                 float* __restrict__ norm2) {
    const int lane = threadIdx.x & 63;
    const int row = blockIdx.x * 4 + (threadIdx.x >> 6);
    const int start = row_start[row], end = row_start[row + 1];
    const float si = s[row];
    for (int e = start + lane; e < end; e += 64) {
        const int j = col[e];
        const float x = si + t[j];
        const float lr = x > 0.f ? x : 0.2f * x;
        int c = 0;
        for (int q = start; q < end; ++q) c += (col[q] == j) ? 1 : 0;
        lr_e[e] = lr;
        atomicAdd(&norm2[j], (float)c * lr * lr);
    }
}

__global__ __launch_bounds__(256) void k_inv(float* __restrict__ norm2) {
    const int i = blockIdx.x * 256 + threadIdx.x;
    const float n = norm2[i];
    norm2[i] = 1.0f / fmaxf(sqrtf(n), 1e-12f);
}

// ---------- out[i,:] = sum_{edges (i,j)} (lr/norm_j) * HW[j,:] ----------
__global__ __launch_bounds__(256) void k_spmm(const int* __restrict__ row_start,
                                              const int* __restrict__ col,
                                              const float* __restrict__ lr_e,
                                              const float* __restrict__ inv_n,
                                              const float* __restrict__ HW,
                                              float* __restrict__ out) {
    const int lane = threadIdx.x & 63;
    const int row = blockIdx.x * 4 + (threadIdx.x >> 6);
    const int start = row_start[row], end = row_start[row + 1];
    float acc0 = 0.f, acc1 = 0.f;
    for (int e = start; e < end; ++e) {
        const int j = col[e];
        const float coef = lr_e[e] * inv_n[j];
        acc0 += coef * HW[j * 128 + lane];
        acc1 += coef * HW[j * 128 + 64 + lane];
    }
    out[row * 128 + lane] = acc0;
    out[row * 128 + 64 + lane] = acc1;
}

extern "C" void kernel_launch(void* const* d_in, const int* in_sizes, int n_in,
                              void* d_out, int out_size, void* d_ws, size_t ws_size,
                              hipStream_t stream) {
    const float* feat = (const float*)d_in[0];
    const float* Wm = (const float*)d_in[1];
    const float* a = (const float*)d_in[2];
    const int* edges = (const int*)d_in[3];
    const int* src = edges;
    const int* dst = edges + NE;
    float* out = (float*)d_out;

    // workspace layout (floats/ints, ~6.5 MB total)
    float* HW = (float*)d_ws;              // NN*128
    float* s = HW + NN * 128;              // NN
    float* t = s + NN;                     // NN
    float* lr_e = t + NN;                  // NE
    float* norm2 = lr_e + NE;              // NN (becomes 1/norm in place)
    int* cnt = (int*)(norm2 + NN);         // NN
    int* row_start = cnt + NN;             // NN+1
    int* cur_ofs = row_start + NN + 1;     // NN
    int* col = cur_ofs + NN;               // NE

    // zero norm2 + cnt (adjacent) — ws is poisoned 0xAA before every launch
    hipMemsetAsync(norm2, 0, 2 * NN * sizeof(float), stream);

    k_gemm<<<NN / 16, 256, 0, stream>>>(feat, Wm, HW);
    k_st<<<NN / 4, 256, 0, stream>>>(HW, a, s, t);
    k_count<<<NE / 256, 256, 0, stream>>>(src, cnt);
    k_scan<<<1, 1024, 0, stream>>>(cnt, row_start, cur_ofs);
    k_scatter<<<NE / 256, 256, 0, stream>>>(src, dst, cur_ofs, col);
    k_dupnorm<<<NN / 4, 256, 0, stream>>>(row_start, col, s, t, lr_e, norm2);
    k_inv<<<NN / 256, 256, 0, stream>>>(norm2);
    k_spmm<<<NN / 4, 256, 0, stream>>>(row_start, col, lr_e, norm2, HW, out);
}

// Round 2
// 152.739 us; speedup vs baseline: 1.0539x; 1.0539x over previous
//
#include <hip/hip_runtime.h>

#define NN 8192
#define NE 262144

// ---------- Phase 1: blocks [0,512) do HW = feat@W (16 rows each);
//            blocks [512,1536) do degree histogram of src. ----------
__global__ __launch_bounds__(256) void k_phase1(const float* __restrict__ feat,
                                                const float* __restrict__ Wm,
                                                float* __restrict__ HW,
                                                const int* __restrict__ src,
                                                int* __restrict__ cnt) {
    const int b = blockIdx.x;
    const int tid = threadIdx.x;
    if (b < 512) {
        __shared__ float fs[16 * 256];
        const int f = tid & 127;
        const int rh = tid >> 7;
        const int row0 = b * 16;
        for (int idx = tid * 4; idx < 16 * 256; idx += 256 * 4) {
            *(float4*)&fs[idx] = *(const float4*)&feat[row0 * 256 + idx];
        }
        __syncthreads();
        float acc[8];
#pragma unroll
        for (int r = 0; r < 8; ++r) acc[r] = 0.f;
        const float* fsr = fs + rh * 8 * 256;
        for (int k = 0; k < 256; k += 4) {
            const float w0 = Wm[(k + 0) * 128 + f];
            const float w1 = Wm[(k + 1) * 128 + f];
            const float w2 = Wm[(k + 2) * 128 + f];
            const float w3 = Wm[(k + 3) * 128 + f];
#pragma unroll
            for (int r = 0; r < 8; ++r) {
                const float4 fv = *(const float4*)&fsr[r * 256 + k];
                acc[r] += fv.x * w0 + fv.y * w1 + fv.z * w2 + fv.w * w3;
            }
        }
#pragma unroll
        for (int r = 0; r < 8; ++r) {
            HW[(row0 + rh * 8 + r) * 128 + f] = acc[r];
        }
    } else {
        const int e = (b - 512) * 256 + tid;
        atomicAdd(&cnt[src[e]], 1);
    }
}

// ---------- Phase 2: block 0 scans degrees -> row_start/cur_ofs;
//            blocks [1,513) compute s,t (16 rows each, 1 wave/row). ----------
__global__ __launch_bounds__(1024) void k_phase2(const int* __restrict__ cnt,
                                                 int* __restrict__ row_start,
                                                 int* __restrict__ cur_ofs,
                                                 const float* __restrict__ HW,
                                                 const float* __restrict__ a,
                                                 float* __restrict__ s,
                                                 float* __restrict__ t) {
    if (blockIdx.x == 0) {
        __shared__ int part[1024];
        const int tid = threadIdx.x;
        int c[8];
        int sum = 0;
#pragma unroll
        for (int r = 0; r < 8; ++r) { c[r] = cnt[tid * 8 + r]; sum += c[r]; }
        part[tid] = sum;
        __syncthreads();
        for (int off = 1; off < 1024; off <<= 1) {
            int v = part[tid];
            if (tid >= off) v += part[tid - off];
            __syncthreads();
            part[tid] = v;
            __syncthreads();
        }
        int run = (tid == 0) ? 0 : part[tid - 1];
#pragma unroll
        for (int r = 0; r < 8; ++r) {
            const int row = tid * 8 + r;
            row_start[row] = run;
            cur_ofs[row] = run;
            run += c[r];
        }
        if (tid == 1023) row_start[NN] = part[1023];
    } else {
        const int lane = threadIdx.x & 63;
        const int row = (blockIdx.x - 1) * 16 + (threadIdx.x >> 6);
        const float* h = HW + row * 128;
        const float v0 = h[lane], v1 = h[64 + lane];
        float su = v0 * a[lane] + v1 * a[64 + lane];
        float tu = v0 * a[128 + lane] + v1 * a[192 + lane];
        for (int off = 32; off; off >>= 1) {
            su += __shfl_xor(su, off);
            tu += __shfl_xor(tu, off);
        }
        if (lane == 0) { s[row] = su; t[row] = tu; }
    }
}

// ---------- Phase 3: scatter edges into CSR col[] ----------
__global__ __launch_bounds__(256) void k_scatter(const int* __restrict__ src,
                                                 const int* __restrict__ dst,
                                                 int* __restrict__ cur_ofs,
                                                 int* __restrict__ col) {
    const int e = blockIdx.x * 256 + threadIdx.x;
    const int i = src[e];
    const int pos = atomicAdd(&cur_ofs[i], 1);
    col[pos] = dst[e];
}

// ---------- Phase 4: per-edge leakyrelu + multiplicity + column-norm acc ----------
// norm2[j] += c * lr^2 per instance  (sums to (c*lr)^2 per distinct cell)
__global__ __launch_bounds__(256) void k_dupnorm(const int* __restrict__ row_start,
                                                 const int* __restrict__ col,
                                                 const float* __restrict__ s,
                                                 const float* __restrict__ t,
                                                 float* __restrict__ lr_e,
                                                 float* __restrict__ norm2) {
    const int lane = threadIdx.x & 63;
    const int row = blockIdx.x * 4 + (threadIdx.x >> 6);
    const int start = row_start[row], end = row_start[row + 1];
    const float si = s[row];
    for (int e = start + lane; e < end; e += 64) {
        const int j = col[e];
        const float x = si + t[j];
        const float lr = x > 0.f ? x : 0.2f * x;
        int c = 0;
        for (int q = start; q < end; ++q) c += (col[q] == j) ? 1 : 0;
        lr_e[e] = lr;
        atomicAdd(&norm2[j], (float)c * lr * lr);
    }
}

// ---------- Phase 5: out[i,:] = sum_edges lr/max(sqrt(norm2[j]),eps) * HW[j,:] ----------
__global__ __launch_bounds__(256) void k_spmm(const int* __restrict__ row_start,
                                              const int* __restrict__ col,
                                              const float* __restrict__ lr_e,
                                              const float* __restrict__ norm2,
                                              const float* __restrict__ HW,
                                              float* __restrict__ out) {
    const int lane = threadIdx.x & 63;
    const int row = blockIdx.x * 4 + (threadIdx.x >> 6);
    const int start = row_start[row], end = row_start[row + 1];
    float a0 = 0.f, a1 = 0.f, b0 = 0.f, b1 = 0.f;
    int e = start;
    for (; e + 1 < end; e += 2) {
        const int j0 = col[e];
        const int j1 = col[e + 1];
        const float c0 = lr_e[e] / fmaxf(sqrtf(norm2[j0]), 1e-12f);
        const float c1 = lr_e[e + 1] / fmaxf(sqrtf(norm2[j1]), 1e-12f);
        a0 += c0 * HW[j0 * 128 + lane];
        a1 += c0 * HW[j0 * 128 + 64 + lane];
        b0 += c1 * HW[j1 * 128 + lane];
        b1 += c1 * HW[j1 * 128 + 64 + lane];
    }
    if (e < end) {
        const int j0 = col[e];
        const float c0 = lr_e[e] / fmaxf(sqrtf(norm2[j0]), 1e-12f);
        a0 += c0 * HW[j0 * 128 + lane];
        a1 += c0 * HW[j0 * 128 + 64 + lane];
    }
    out[row * 128 + lane] = a0 + b0;
    out[row * 128 + 64 + lane] = a1 + b1;
}

extern "C" void kernel_launch(void* const* d_in, const int* in_sizes, int n_in,
                              void* d_out, int out_size, void* d_ws, size_t ws_size,
                              hipStream_t stream) {
    const float* feat = (const float*)d_in[0];
    const float* Wm = (const float*)d_in[1];
    const float* a = (const float*)d_in[2];
    const int* edges = (const int*)d_in[3];
    const int* src = edges;
    const int* dst = edges + NE;
    float* out = (float*)d_out;

    // workspace layout
    float* HW = (float*)d_ws;              // NN*128
    float* s = HW + NN * 128;              // NN
    float* t = s + NN;                     // NN
    float* lr_e = t + NN;                  // NE
    float* norm2 = lr_e + NE;              // NN
    int* cnt = (int*)(norm2 + NN);         // NN
    int* row_start = cnt + NN;             // NN+1
    int* cur_ofs = row_start + NN + 1;     // NN
    int* col = cur_ofs + NN;               // NE

    hipMemsetAsync(norm2, 0, 2 * NN * sizeof(float), stream);  // norm2 + cnt

    k_phase1<<<512 + NE / 256, 256, 0, stream>>>(feat, Wm, HW, src, cnt);
    k_phase2<<<1 + NN / 16, 1024, 0, stream>>>(cnt, row_start, cur_ofs, HW, a, s, t);
    k_scatter<<<NE / 256, 256, 0, stream>>>(src, dst, cur_ofs, col);
    k_dupnorm<<<NN / 4, 256, 0, stream>>>(row_start, col, s, t, lr_e, norm2);
    k_spmm<<<NN / 4, 256, 0, stream>>>(row_start, col, lr_e, norm2, HW, out);
}

// Round 5
// 125.635 us; speedup vs baseline: 1.2812x; 1.2157x over previous
//
#include <hip/hip_runtime.h>

#define NN 8192
#define NE 262144
#define CAP 128

// ---------- Phase 1: blocks [0,512) GEMM (16 rows) + s,t epilogue;
//            blocks [512,1536): one-pass count+scatter into fixed-cap buckets. ----------
__global__ __launch_bounds__(256) void k_fused1(const float* __restrict__ feat,
                                                const float* __restrict__ Wm,
                                                float* __restrict__ HW,
                                                float* __restrict__ s,
                                                float* __restrict__ t,
                                                const float* __restrict__ a,
                                                const int* __restrict__ src,
                                                const int* __restrict__ dst,
                                                int* __restrict__ cnt,
                                                int* __restrict__ col) {
    const int b = blockIdx.x;
    const int tid = threadIdx.x;
    if (b >= 512) {
        // count+scatter: atomic bump gives the slot directly (no CSR scan needed)
        const int e = (b - 512) * 256 + tid;
        const int i = src[e];
        const int pos = atomicAdd(&cnt[i], 1);
        if (pos < CAP) col[i * CAP + pos] = dst[e];  // deg>128 is ~1e-20 probability
        return;
    }
    __shared__ float fs[16 * 256];
    __shared__ float red[2][4][8];  // [s|t][wave][row-in-half]
    const int f = tid & 127;
    const int rh = tid >> 7;
    const int row0 = b * 16;
    for (int idx = tid * 4; idx < 16 * 256; idx += 256 * 4) {
        *(float4*)&fs[idx] = *(const float4*)&feat[row0 * 256 + idx];
    }
    __syncthreads();
    float acc[8];
#pragma unroll
    for (int r = 0; r < 8; ++r) acc[r] = 0.f;
    const float* fsr = fs + rh * 8 * 256;
    for (int k = 0; k < 256; k += 4) {
        const float w0 = Wm[(k + 0) * 128 + f];
        const float w1 = Wm[(k + 1) * 128 + f];
        const float w2 = Wm[(k + 2) * 128 + f];
        const float w3 = Wm[(k + 3) * 128 + f];
#pragma unroll
        for (int r = 0; r < 8; ++r) {
            const float4 fv = *(const float4*)&fsr[r * 256 + k];
            acc[r] += fv.x * w0 + fv.y * w1 + fv.z * w2 + fv.w * w3;
        }
    }
#pragma unroll
    for (int r = 0; r < 8; ++r) {
        HW[(row0 + rh * 8 + r) * 128 + f] = acc[r];
    }
    // epilogue: s_i = HW_i . a[:128], t_i = HW_i . a[128:]
    const float as_ = a[f];
    const float at_ = a[128 + f];
    const int w = tid >> 6;
    const int lane = tid & 63;
#pragma unroll
    for (int r = 0; r < 8; ++r) {
        float vs = acc[r] * as_;
        float vt = acc[r] * at_;
        for (int off = 32; off; off >>= 1) {
            vs += __shfl_xor(vs, off);
            vt += __shfl_xor(vt, off);
        }
        if (lane == 0) { red[0][w][r] = vs; red[1][w][r] = vt; }
    }
    __syncthreads();
    // waves 0,1 cover rows 0-7 (two f-halves); waves 2,3 cover rows 8-15
    if (tid < 8)       s[row0 + tid] = red[0][0][tid] + red[0][1][tid];
    else if (tid < 16) s[row0 + tid] = red[0][2][tid - 8] + red[0][3][tid - 8];
    else if (tid < 24) t[row0 + (tid - 16)] = red[1][0][tid - 16] + red[1][1][tid - 16];
    else if (tid < 32) t[row0 + 8 + (tid - 24)] = red[1][2][tid - 24] + red[1][3][tid - 24];
}

// ---------- Phase 2: per-edge multiplicity + column-norm accumulation ----------
// norm2[j] += c * lr^2 per instance (sums to (c*lr)^2 per distinct cell)
__global__ __launch_bounds__(256) void k_dupnorm(const int* __restrict__ cnt,
                                                 const int* __restrict__ col,
                                                 const float* __restrict__ s,
                                                 const float* __restrict__ t,
                                                 float* __restrict__ norm2) {
    __shared__ int cs[4][CAP];
    const int lane = threadIdx.x & 63;
    const int w = threadIdx.x >> 6;
    const int row = blockIdx.x * 4 + w;
    const int deg = min(cnt[row], CAP);
    int jA = -1, jB = -1;
    if (lane < deg) jA = col[row * CAP + lane];
    if (64 + lane < deg) jB = col[row * CAP + 64 + lane];
    cs[w][lane] = jA;
    cs[w][64 + lane] = jB;
    __syncthreads();
    const float si = s[row];
    float lrA = 0.f, lrB = 0.f;
    if (jA >= 0) { const float x = si + t[jA]; lrA = x > 0.f ? x : 0.2f * x; }
    if (jB >= 0) { const float x = si + t[jB]; lrB = x > 0.f ? x : 0.2f * x; }
    int cA = 0, cB = 0;
    for (int q = 0; q < deg; ++q) {
        const int v = cs[w][q];  // same addr across lanes -> LDS broadcast
        cA += (v == jA);
        cB += (v == jB);
    }
    if (jA >= 0) atomicAdd(&norm2[jA], (float)cA * lrA * lrA);
    if (jB >= 0) atomicAdd(&norm2[jB], (float)cB * lrB * lrB);
}

// ---------- Phase 3: out[i,:] = sum_edges lr/max(sqrt(norm2[j]),eps) * HW[j,:] ----------
__global__ __launch_bounds__(256) void k_spmm(const int* __restrict__ cnt,
                                              const int* __restrict__ col,
                                              const float* __restrict__ s,
                                              const float* __restrict__ t,
                                              const float* __restrict__ norm2,
                                              const float* __restrict__ HW,
                                              float* __restrict__ out) {
    const int lane = threadIdx.x & 63;
    const int w = threadIdx.x >> 6;
    const int row = blockIdx.x * 2 + (w >> 1);
    const int f = (w & 1) * 64 + lane;
    const int deg = min(cnt[row], CAP);
    const float si = s[row];
    int j0 = 0;
    float c0 = 0.f;
    if (lane < deg) {
        j0 = col[row * CAP + lane];
        const float x = si + t[j0];
        const float lr = x > 0.f ? x : 0.2f * x;
        c0 = lr / fmaxf(sqrtf(norm2[j0]), 1e-12f);
    }
    float a0 = 0.f, a1 = 0.f, a2 = 0.f, a3 = 0.f;
    const int d0 = min(deg, 64);
    int e = 0;
    for (; e + 3 < d0; e += 4) {
        const int ja = __shfl(j0, e), jb = __shfl(j0, e + 1);
        const int jc = __shfl(j0, e + 2), jd = __shfl(j0, e + 3);
        const float ca = __shfl(c0, e), cb = __shfl(c0, e + 1);
        const float cc = __shfl(c0, e + 2), cd = __shfl(c0, e + 3);
        a0 += ca * HW[ja * 128 + f];
        a1 += cb * HW[jb * 128 + f];
        a2 += cc * HW[jc * 128 + f];
        a3 += cd * HW[jd * 128 + f];
    }
    for (; e < d0; ++e) {
        a0 += __shfl(c0, e) * HW[__shfl(j0, e) * 128 + f];
    }
    if (deg > 64) {  // wave-uniform branch, essentially never taken
        int j1 = 0;
        float c1 = 0.f;
        if (64 + lane < deg) {
            j1 = col[row * CAP + 64 + lane];
            const float x = si + t[j1];
            const float lr = x > 0.f ? x : 0.2f * x;
            c1 = lr / fmaxf(sqrtf(norm2[j1]), 1e-12f);
        }
        const int d1 = deg - 64;
        for (e = 0; e < d1; ++e) {
            a0 += __shfl(c1, e) * HW[__shfl(j1, e) * 128 + f];
        }
    }
    out[row * 128 + f] = a0 + a1 + a2 + a3;
}

extern "C" void kernel_launch(void* const* d_in, const int* in_sizes, int n_in,
                              void* d_out, int out_size, void* d_ws, size_t ws_size,
                              hipStream_t stream) {
    const float* feat = (const float*)d_in[0];
    const float* Wm = (const float*)d_in[1];
    const float* a = (const float*)d_in[2];
    const int* edges = (const int*)d_in[3];
    const int* src = edges;
    const int* dst = edges + NE;
    float* out = (float*)d_out;

    // workspace layout (~12.3 MB)
    float* HW = (float*)d_ws;            // NN*128
    float* s = HW + NN * 128;            // NN
    float* t = s + NN;                   // NN
    float* norm2 = t + NN;               // NN  \ adjacent: one memset
    int* cnt = (int*)(norm2 + NN);       // NN  /
    int* col = cnt + NN;                 // NN*CAP

    hipMemsetAsync(norm2, 0, 2 * NN * sizeof(float), stream);

    k_fused1<<<512 + NE / 256, 256, 0, stream>>>(feat, Wm, HW, s, t, a, src, dst, cnt, col);
    k_dupnorm<<<NN / 4, 256, 0, stream>>>(cnt, col, s, t, norm2);
    k_spmm<<<NN / 2, 256, 0, stream>>>(cnt, col, s, t, norm2, HW, out);
}

// Round 8
// 124.330 us; speedup vs baseline: 1.2947x; 1.0105x over previous
//
#include <hip/hip_runtime.h>
#include <hip/hip_bf16.h>

#define NN 8192
#define NE 262144
#define CAP 128

// ---------- Phase 1: blocks [0,512) GEMM (16 rows, 4 waves x 4 rows, 2 f-cols/thread,
//            fp32 compute -> bf16 HW store) + s,t epilogue (wave-local);
//            blocks [512,1536): one-pass count+scatter into fixed-cap buckets. ----------
__global__ __launch_bounds__(256) void k_fused1(const float* __restrict__ feat,
                                                const float* __restrict__ Wm,
                                                const float* __restrict__ a,
                                                const int* __restrict__ src,
                                                const int* __restrict__ dst,
                                                __hip_bfloat16* __restrict__ HWb,
                                                float* __restrict__ s,
                                                float* __restrict__ t,
                                                int* __restrict__ cnt,
                                                int* __restrict__ col) {
    const int b = blockIdx.x;
    const int tid = threadIdx.x;
    if (b >= 512) {
        // count+scatter: atomic bump gives the slot directly (no CSR scan)
        const int e = (b - 512) * 256 + tid;
        const int i = src[e];
        const int pos = atomicAdd(&cnt[i], 1);
        if (pos < CAP) col[i * CAP + pos] = dst[e];  // deg>128 ~ 1e-20 prob
        return;
    }
    __shared__ float fs[16 * 256];
    const int fq = tid & 63;   // f-pair: f0 = fq, f1 = fq + 64
    const int w = tid >> 6;    // wave owns rows w*4 .. w*4+3
    const int row0 = b * 16;
    for (int idx = tid * 4; idx < 16 * 256; idx += 256 * 4)
        *(float4*)&fs[idx] = *(const float4*)&feat[row0 * 256 + idx];
    __syncthreads();
    float acc[4][2] = {};
    const float* fsr = fs + w * 4 * 256;
    for (int k = 0; k < 256; k += 4) {
        float4 fv[4];
#pragma unroll
        for (int r = 0; r < 4; ++r) fv[r] = *(const float4*)&fsr[r * 256 + k];
        float wv[4][2];
#pragma unroll
        for (int i = 0; i < 4; ++i) {
            wv[i][0] = Wm[(k + i) * 128 + fq];
            wv[i][1] = Wm[(k + i) * 128 + fq + 64];
        }
#pragma unroll
        for (int r = 0; r < 4; ++r) {
            acc[r][0] += fv[r].x * wv[0][0] + fv[r].y * wv[1][0] + fv[r].z * wv[2][0] + fv[r].w * wv[3][0];
            acc[r][1] += fv[r].x * wv[0][1] + fv[r].y * wv[1][1] + fv[r].z * wv[2][1] + fv[r].w * wv[3][1];
        }
    }
    // epilogue: bf16 HW store + wave-local s,t reduction (each wave owns its 4 rows)
    const float aS0 = a[fq], aS1 = a[fq + 64];
    const float aT0 = a[128 + fq], aT1 = a[192 + fq];
#pragma unroll
    for (int r = 0; r < 4; ++r) {
        const int row = row0 + w * 4 + r;
        HWb[row * 128 + fq] = __float2bfloat16(acc[r][0]);
        HWb[row * 128 + fq + 64] = __float2bfloat16(acc[r][1]);
        float vs = acc[r][0] * aS0 + acc[r][1] * aS1;
        float vt = acc[r][0] * aT0 + acc[r][1] * aT1;
        for (int off = 32; off; off >>= 1) {
            vs += __shfl_xor(vs, off);
            vt += __shfl_xor(vt, off);
        }
        if (fq == 0) { s[row] = vs; t[row] = vt; }
    }
}

// ---------- Phase 2: per-edge multiplicity + column-norm accumulation ----------
// norm2[j] += c * lr^2 per instance (sums to (c*lr)^2 per distinct cell)
__global__ __launch_bounds__(256) void k_dupnorm(const int* __restrict__ cnt,
                                                 const int* __restrict__ col,
                                                 const float* __restrict__ s,
                                                 const float* __restrict__ t,
                                                 float* __restrict__ norm2) {
    __shared__ int cs[4][CAP];
    const int lane = threadIdx.x & 63;
    const int w = threadIdx.x >> 6;
    const int row = blockIdx.x * 4 + w;
    const int deg = min(cnt[row], CAP);
    int jA = -1, jB = -1;
    if (lane < deg) jA = col[row * CAP + lane];
    if (64 + lane < deg) jB = col[row * CAP + 64 + lane];
    cs[w][lane] = jA;
    cs[w][64 + lane] = jB;
    __syncthreads();
    const float si = s[row];
    float lrA = 0.f, lrB = 0.f;
    if (jA >= 0) { const float x = si + t[jA]; lrA = x > 0.f ? x : 0.2f * x; }
    if (jB >= 0) { const float x = si + t[jB]; lrB = x > 0.f ? x : 0.2f * x; }
    int cA = 0, cB = 0;
    for (int q = 0; q < deg; ++q) {
        const int v = cs[w][q];  // same addr across lanes -> LDS broadcast
        cA += (v == jA);
        cB += (v == jB);
    }
    if (jA >= 0) atomicAdd(&norm2[jA], (float)cA * lrA * lrA);
    if (jB >= 0) atomicAdd(&norm2[jB], (float)cB * lrB * lrB);
}

// ---------- Phase 3: out[i,:] = sum_edges lr/max(sqrt(norm2[j]),eps) * HW[j,:] ----------
__global__ __launch_bounds__(256) void k_spmm(const int* __restrict__ cnt,
                                              const int* __restrict__ col,
                                              const float* __restrict__ s,
                                              const float* __restrict__ t,
                                              const float* __restrict__ norm2,
                                              const __hip_bfloat16* __restrict__ HWb,
                                              float* __restrict__ out) {
    const int lane = threadIdx.x & 63;
    const int w = threadIdx.x >> 6;
    const int row = blockIdx.x * 2 + (w >> 1);
    const int f = (w & 1) * 64 + lane;
    const int deg = min(cnt[row], CAP);
    const float si = s[row];
    int j0 = 0;
    float c0 = 0.f;
    if (lane < deg) {
        j0 = col[row * CAP + lane];
        const float x = si + t[j0];
        const float lr = x > 0.f ? x : 0.2f * x;
        c0 = lr / fmaxf(sqrtf(norm2[j0]), 1e-12f);
    }
    float a0 = 0.f, a1 = 0.f, a2 = 0.f, a3 = 0.f;
    const int d0 = min(deg, 64);
    int e = 0;
    for (; e + 3 < d0; e += 4) {
        const int ja = __shfl(j0, e), jb = __shfl(j0, e + 1);
        const int jc = __shfl(j0, e + 2), jd = __shfl(j0, e + 3);
        const float ca = __shfl(c0, e), cb = __shfl(c0, e + 1);
        const float cc = __shfl(c0, e + 2), cd = __shfl(c0, e + 3);
        a0 += ca * __bfloat162float(HWb[ja * 128 + f]);
        a1 += cb * __bfloat162float(HWb[jb * 128 + f]);
        a2 += cc * __bfloat162float(HWb[jc * 128 + f]);
        a3 += cd * __bfloat162float(HWb[jd * 128 + f]);
    }
    for (; e < d0; ++e)
        a0 += __shfl(c0, e) * __bfloat162float(HWb[__shfl(j0, e) * 128 + f]);
    if (deg > 64) {  // wave-uniform, essentially never taken
        int j1 = 0;
        float c1 = 0.f;
        if (64 + lane < deg) {
            j1 = col[row * CAP + 64 + lane];
            const float x = si + t[j1];
            const float lr = x > 0.f ? x : 0.2f * x;
            c1 = lr / fmaxf(sqrtf(norm2[j1]), 1e-12f);
        }
        const int d1 = deg - 64;
        for (e = 0; e < d1; ++e)
            a0 += __shfl(c1, e) * __bfloat162float(HWb[__shfl(j1, e) * 128 + f]);
    }
    out[row * 128 + f] = a0 + a1 + a2 + a3;
}

extern "C" void kernel_launch(void* const* d_in, const int* in_sizes, int n_in,
                              void* d_out, int out_size, void* d_ws, size_t ws_size,
                              hipStream_t stream) {
    const float* feat = (const float*)d_in[0];
    const float* Wm = (const float*)d_in[1];
    const float* a = (const float*)d_in[2];
    const int* edges = (const int*)d_in[3];
    const int* src = edges;
    const int* dst = edges + NE;
    float* out = (float*)d_out;

    // workspace layout (~10.3 MB)
    __hip_bfloat16* HWb = (__hip_bfloat16*)d_ws;  // NN*128 bf16 (2 MB)
    float* s = (float*)(HWb + NN * 128);          // NN
    float* t = s + NN;                            // NN
    float* norm2 = t + NN;                        // NN  \ adjacent: one memset
    int* cnt = (int*)(norm2 + NN);                // NN  /
    int* col = cnt + NN;                          // NN*CAP

    hipMemsetAsync(norm2, 0, 2 * NN * sizeof(float), stream);

    k_fused1<<<512 + NE / 256, 256, 0, stream>>>(feat, Wm, a, src, dst, HWb, s, t, cnt, col);
    k_dupnorm<<<NN / 4, 256, 0, stream>>>(cnt, col, s, t, norm2);
    k_spmm<<<NN / 2, 256, 0, stream>>>(cnt, col, s, t, norm2, HWb, out);
}

// Round 9
// 118.109 us; speedup vs baseline: 1.3629x; 1.0527x over previous
//
#include <hip/hip_runtime.h>
#include <hip/hip_bf16.h>

#define NN 8192
#define NE 262144
#define CAP 128

// ---------- Phase 1: blocks [0,512) GEMM (16 rows, 4 waves x 4 rows, 2 f-cols/thread,
//            fp32 compute -> bf16 HW store) + s,t epilogue (wave-local);
//            blocks [512,1536): one-pass count+scatter into fixed-cap buckets. ----------
__global__ __launch_bounds__(256) void k_fused1(const float* __restrict__ feat,
                                                const float* __restrict__ Wm,
                                                const float* __restrict__ a,
                                                const int* __restrict__ src,
                                                const int* __restrict__ dst,
                                                __hip_bfloat16* __restrict__ HWb,
                                                float* __restrict__ s,
                                                float* __restrict__ t,
                                                int* __restrict__ cnt,
                                                int* __restrict__ col) {
    const int b = blockIdx.x;
    const int tid = threadIdx.x;
    if (b >= 512) {
        // count+scatter: atomic bump gives the slot directly (no CSR scan)
        const int e = (b - 512) * 256 + tid;
        const int i = src[e];
        const int pos = atomicAdd(&cnt[i], 1);
        if (pos < CAP) col[i * CAP + pos] = dst[e];  // deg>128 ~ 1e-20 prob
        return;
    }
    __shared__ float fs[16 * 256];
    const int fq = tid & 63;   // f-pair: f0 = fq, f1 = fq + 64
    const int w = tid >> 6;    // wave owns rows w*4 .. w*4+3
    const int row0 = b * 16;
    for (int idx = tid * 4; idx < 16 * 256; idx += 256 * 4)
        *(float4*)&fs[idx] = *(const float4*)&feat[row0 * 256 + idx];
    __syncthreads();
    float acc[4][2] = {};
    const float* fsr = fs + w * 4 * 256;
    for (int k = 0; k < 256; k += 4) {
        float4 fv[4];
#pragma unroll
        for (int r = 0; r < 4; ++r) fv[r] = *(const float4*)&fsr[r * 256 + k];
        float wv[4][2];
#pragma unroll
        for (int i = 0; i < 4; ++i) {
            wv[i][0] = Wm[(k + i) * 128 + fq];
            wv[i][1] = Wm[(k + i) * 128 + fq + 64];
        }
#pragma unroll
        for (int r = 0; r < 4; ++r) {
            acc[r][0] += fv[r].x * wv[0][0] + fv[r].y * wv[1][0] + fv[r].z * wv[2][0] + fv[r].w * wv[3][0];
            acc[r][1] += fv[r].x * wv[0][1] + fv[r].y * wv[1][1] + fv[r].z * wv[2][1] + fv[r].w * wv[3][1];
        }
    }
    // epilogue: bf16 HW store + wave-local s,t reduction (each wave owns its 4 rows)
    const float aS0 = a[fq], aS1 = a[fq + 64];
    const float aT0 = a[128 + fq], aT1 = a[192 + fq];
#pragma unroll
    for (int r = 0; r < 4; ++r) {
        const int row = row0 + w * 4 + r;
        HWb[row * 128 + fq] = __float2bfloat16(acc[r][0]);
        HWb[row * 128 + fq + 64] = __float2bfloat16(acc[r][1]);
        float vs = acc[r][0] * aS0 + acc[r][1] * aS1;
        float vt = acc[r][0] * aT0 + acc[r][1] * aT1;
        for (int off = 32; off; off >>= 1) {
            vs += __shfl_xor(vs, off);
            vt += __shfl_xor(vt, off);
        }
        if (fq == 0) { s[row] = vs; t[row] = vt; }
    }
}

// ---------- Phase 2: per-edge multiplicity + column-norm accumulation ----------
// norm2[j] += c * lr^2 per instance (sums to (c*lr)^2 per distinct cell)
__global__ __launch_bounds__(256) void k_dupnorm(const int* __restrict__ cnt,
                                                 const int* __restrict__ col,
                                                 const float* __restrict__ s,
                                                 const float* __restrict__ t,
                                                 float* __restrict__ norm2) {
    __shared__ int cs[4][CAP];
    const int lane = threadIdx.x & 63;
    const int w = threadIdx.x >> 6;
    const int row = blockIdx.x * 4 + w;
    const int deg = min(cnt[row], CAP);
    int jA = -1, jB = -1;
    if (lane < deg) jA = col[row * CAP + lane];
    if (64 + lane < deg) jB = col[row * CAP + 64 + lane];
    cs[w][lane] = jA;
    cs[w][64 + lane] = jB;
    __syncthreads();
    const float si = s[row];
    float lrA = 0.f, lrB = 0.f;
    if (jA >= 0) { const float x = si + t[jA]; lrA = x > 0.f ? x : 0.2f * x; }
    if (jB >= 0) { const float x = si + t[jB]; lrB = x > 0.f ? x : 0.2f * x; }
    int cA = 0, cB = 0;
    for (int q = 0; q < deg; ++q) {
        const int v = cs[w][q];  // same addr across lanes -> LDS broadcast
        cA += (v == jA);
        cB += (v == jB);
    }
    if (jA >= 0) atomicAdd(&norm2[jA], (float)cA * lrA * lrA);
    if (jB >= 0) atomicAdd(&norm2[jB], (float)cB * lrB * lrB);
}

// ---------- Phase 3: out[i,:] = sum_edges lr/max(sqrt(norm2[j]),eps) * HW[j,:] ----------
// One wave per row. Lane l owns feature pair (2l, 2l+1); per edge j the wave
// loads row j of HW as 64 packed uint (2x bf16) -> 2 x 128B transactions.
__global__ __launch_bounds__(256) void k_spmm(const int* __restrict__ cnt,
                                              const int* __restrict__ col,
                                              const float* __restrict__ s,
                                              const float* __restrict__ t,
                                              const float* __restrict__ norm2,
                                              const __hip_bfloat16* __restrict__ HWb,
                                              float* __restrict__ out) {
    const int lane = threadIdx.x & 63;
    const int w = threadIdx.x >> 6;
    const int row = blockIdx.x * 4 + w;
    const int deg = min(cnt[row], CAP);
    const float si = s[row];
    const uint* __restrict__ HW2 = (const uint*)HWb;  // HW2[j*64 + l] = feats (2l, 2l+1)
    // per-lane edge precompute: lane e holds (j, coef) for edge e of this row
    int jA = 0;
    float cA = 0.f;
    if (lane < deg) {
        jA = col[row * CAP + lane];
        const float x = si + t[jA];
        const float lr = x > 0.f ? x : 0.2f * x;
        cA = lr / fmaxf(sqrtf(norm2[jA]), 1e-12f);
    }
    float a0 = 0.f, a1 = 0.f, b0 = 0.f, b1 = 0.f;
    const int d0 = min(deg, 64);
    int e = 0;
    for (; e + 3 < d0; e += 4) {
        const int j0 = __shfl(jA, e), j1 = __shfl(jA, e + 1);
        const int j2 = __shfl(jA, e + 2), j3 = __shfl(jA, e + 3);
        const float c0 = __shfl(cA, e), c1 = __shfl(cA, e + 1);
        const float c2 = __shfl(cA, e + 2), c3 = __shfl(cA, e + 3);
        const uint u0 = HW2[j0 * 64 + lane];
        const uint u1 = HW2[j1 * 64 + lane];
        const uint u2 = HW2[j2 * 64 + lane];
        const uint u3 = HW2[j3 * 64 + lane];
        a0 += c0 * __uint_as_float(u0 << 16);
        a1 += c0 * __uint_as_float(u0 & 0xFFFF0000u);
        b0 += c1 * __uint_as_float(u1 << 16);
        b1 += c1 * __uint_as_float(u1 & 0xFFFF0000u);
        a0 += c2 * __uint_as_float(u2 << 16);
        a1 += c2 * __uint_as_float(u2 & 0xFFFF0000u);
        b0 += c3 * __uint_as_float(u3 << 16);
        b1 += c3 * __uint_as_float(u3 & 0xFFFF0000u);
    }
    for (; e < d0; ++e) {
        const int j0 = __shfl(jA, e);
        const float c0 = __shfl(cA, e);
        const uint u0 = HW2[j0 * 64 + lane];
        a0 += c0 * __uint_as_float(u0 << 16);
        a1 += c0 * __uint_as_float(u0 & 0xFFFF0000u);
    }
    if (deg > 64) {  // wave-uniform, essentially never taken
        int jB = 0;
        float cB = 0.f;
        if (64 + lane < deg) {
            jB = col[row * CAP + 64 + lane];
            const float x = si + t[jB];
            const float lr = x > 0.f ? x : 0.2f * x;
            cB = lr / fmaxf(sqrtf(norm2[jB]), 1e-12f);
        }
        const int d1 = deg - 64;
        for (e = 0; e < d1; ++e) {
            const int j0 = __shfl(jB, e);
            const float c0 = __shfl(cB, e);
            const uint u0 = HW2[j0 * 64 + lane];
            a0 += c0 * __uint_as_float(u0 << 16);
            a1 += c0 * __uint_as_float(u0 & 0xFFFF0000u);
        }
    }
    // lane l writes features (2l, 2l+1): coalesced float2
    float2 o;
    o.x = a0 + b0;
    o.y = a1 + b1;
    *(float2*)&out[row * 128 + 2 * lane] = o;
}

extern "C" void kernel_launch(void* const* d_in, const int* in_sizes, int n_in,
                              void* d_out, int out_size, void* d_ws, size_t ws_size,
                              hipStream_t stream) {
    const float* feat = (const float*)d_in[0];
    const float* Wm = (const float*)d_in[1];
    const float* a = (const float*)d_in[2];
    const int* edges = (const int*)d_in[3];
    const int* src = edges;
    const int* dst = edges + NE;
    float* out = (float*)d_out;

    // workspace layout (~10.3 MB)
    __hip_bfloat16* HWb = (__hip_bfloat16*)d_ws;  // NN*128 bf16 (2 MB)
    float* s = (float*)(HWb + NN * 128);          // NN
    float* t = s + NN;                            // NN
    float* norm2 = t + NN;                        // NN  \ adjacent: one memset
    int* cnt = (int*)(norm2 + NN);                // NN  /
    int* col = cnt + NN;                          // NN*CAP

    hipMemsetAsync(norm2, 0, 2 * NN * sizeof(float), stream);

    k_fused1<<<512 + NE / 256, 256, 0, stream>>>(feat, Wm, a, src, dst, HWb, s, t, cnt, col);
    k_dupnorm<<<NN / 4, 256, 0, stream>>>(cnt, col, s, t, norm2);
    k_spmm<<<NN / 4, 256, 0, stream>>>(cnt, col, s, t, norm2, HWb, out);
}

// Round 11
// 117.911 us; speedup vs baseline: 1.3652x; 1.0017x over previous
//
#include <hip/hip_runtime.h>
#include <hip/hip_bf16.h>

#define NN 8192
#define NE 262144
#define CAP 128

// ---------- Phase 1: blocks [0,512) GEMM (16 rows, 4 waves x 4 rows, 2 f-cols/thread,
//            fp32 compute -> bf16 HW store) + s,t epilogue (wave-local);
//            blocks [512,1536): one-pass count+scatter into fixed-cap buckets. ----------
__global__ __launch_bounds__(256) void k_fused1(const float* __restrict__ feat,
                                                const float* __restrict__ Wm,
                                                const float* __restrict__ a,
                                                const int* __restrict__ src,
                                                const int* __restrict__ dst,
                                                __hip_bfloat16* __restrict__ HWb,
                                                float* __restrict__ s,
                                                float* __restrict__ t,
                                                int* __restrict__ cnt,
                                                int* __restrict__ col) {
    const int b = blockIdx.x;
    const int tid = threadIdx.x;
    if (b >= 512) {
        // count+scatter: atomic bump gives the slot directly (no CSR scan)
        const int e = (b - 512) * 256 + tid;
        const int i = src[e];
        const int pos = atomicAdd(&cnt[i], 1);
        if (pos < CAP) col[i * CAP + pos] = dst[e];  // deg>128 ~ 1e-20 prob
        return;
    }
    __shared__ float fs[16 * 256];
    const int fq = tid & 63;   // f-pair: f0 = fq, f1 = fq + 64
    const int w = tid >> 6;    // wave owns rows w*4 .. w*4+3
    const int row0 = b * 16;
    for (int idx = tid * 4; idx < 16 * 256; idx += 256 * 4)
        *(float4*)&fs[idx] = *(const float4*)&feat[row0 * 256 + idx];
    __syncthreads();
    float acc[4][2] = {};
    const float* fsr = fs + w * 4 * 256;
    for (int k = 0; k < 256; k += 4) {
        float4 fv[4];
#pragma unroll
        for (int r = 0; r < 4; ++r) fv[r] = *(const float4*)&fsr[r * 256 + k];
        float wv[4][2];
#pragma unroll
        for (int i = 0; i < 4; ++i) {
            wv[i][0] = Wm[(k + i) * 128 + fq];
            wv[i][1] = Wm[(k + i) * 128 + fq + 64];
        }
#pragma unroll
        for (int r = 0; r < 4; ++r) {
            acc[r][0] += fv[r].x * wv[0][0] + fv[r].y * wv[1][0] + fv[r].z * wv[2][0] + fv[r].w * wv[3][0];
            acc[r][1] += fv[r].x * wv[0][1] + fv[r].y * wv[1][1] + fv[r].z * wv[2][1] + fv[r].w * wv[3][1];
        }
    }
    // epilogue: bf16 HW store + wave-local s,t reduction (each wave owns its 4 rows)
    const float aS0 = a[fq], aS1 = a[fq + 64];
    const float aT0 = a[128 + fq], aT1 = a[192 + fq];
#pragma unroll
    for (int r = 0; r < 4; ++r) {
        const int row = row0 + w * 4 + r;
        HWb[row * 128 + fq] = __float2bfloat16(acc[r][0]);
        HWb[row * 128 + fq + 64] = __float2bfloat16(acc[r][1]);
        float vs = acc[r][0] * aS0 + acc[r][1] * aS1;
        float vt = acc[r][0] * aT0 + acc[r][1] * aT1;
        for (int off = 32; off; off >>= 1) {
            vs += __shfl_xor(vs, off);
            vt += __shfl_xor(vt, off);
        }
        if (fq == 0) { s[row] = vs; t[row] = vt; }
    }
}

// ---------- Phase 2: per-edge multiplicity + column-norm accumulation ----------
// norm2[j] += c * lr^2 per instance (sums to (c*lr)^2 per distinct cell)
__global__ __launch_bounds__(256) void k_dupnorm(const int* __restrict__ cnt,
                                                 const int* __restrict__ col,
                                                 const float* __restrict__ s,
                                                 const float* __restrict__ t,
                                                 float* __restrict__ norm2) {
    __shared__ int cs[4][CAP];
    const int lane = threadIdx.x & 63;
    const int w = threadIdx.x >> 6;
    const int row = blockIdx.x * 4 + w;
    const int deg = min(cnt[row], CAP);
    int jA = -1, jB = -1;
    if (lane < deg) jA = col[row * CAP + lane];
    if (64 + lane < deg) jB = col[row * CAP + 64 + lane];
    cs[w][lane] = jA;
    cs[w][64 + lane] = jB;
    __syncthreads();
    const float si = s[row];
    float lrA = 0.f, lrB = 0.f;
    if (jA >= 0) { const float x = si + t[jA]; lrA = x > 0.f ? x : 0.2f * x; }
    if (jB >= 0) { const float x = si + t[jB]; lrB = x > 0.f ? x : 0.2f * x; }
    int cA = 0, cB = 0;
    for (int q = 0; q < deg; ++q) {
        const int v = cs[w][q];  // same addr across lanes -> LDS broadcast
        cA += (v == jA);
        cB += (v == jB);
    }
    if (jA >= 0) atomicAdd(&norm2[jA], (float)cA * lrA * lrA);
    if (jB >= 0) atomicAdd(&norm2[jB], (float)cB * lrB * lrB);
}

// ---------- Phase 3: out[i,:] = sum_edges lr/max(sqrt(norm2[j]),eps) * HW[j,:] ----------
// One wave per row; lane l owns feature pair (2l, 2l+1). Unroll 8: 8 outstanding
// 4B gathers per wave iteration (spmm is issue/latency-bound per R8->R9 A/B).
__global__ __launch_bounds__(256) void k_spmm(const int* __restrict__ cnt,
                                              const int* __restrict__ col,
                                              const float* __restrict__ s,
                                              const float* __restrict__ t,
                                              const float* __restrict__ norm2,
                                              const __hip_bfloat16* __restrict__ HWb,
                                              float* __restrict__ out) {
    const int lane = threadIdx.x & 63;
    const int w = threadIdx.x >> 6;
    const int row = blockIdx.x * 4 + w;
    const int deg = min(cnt[row], CAP);
    const float si = s[row];
    const uint* __restrict__ HW2 = (const uint*)HWb;  // HW2[j*64 + l] = feats (2l, 2l+1)
    // per-lane edge precompute: lane e holds (j, coef) for edge e of this row
    int jA = 0;
    float cA = 0.f;
    if (lane < deg) {
        jA = col[row * CAP + lane];
        const float x = si + t[jA];
        const float lr = x > 0.f ? x : 0.2f * x;
        cA = lr / fmaxf(sqrtf(norm2[jA]), 1e-12f);
    }
    float a0 = 0.f, a1 = 0.f, b0 = 0.f, b1 = 0.f;
    const int d0 = min(deg, 64);
    int e = 0;
    for (; e + 7 < d0; e += 8) {
        int jj[8];
        float cc[8];
        uint uu[8];
#pragma unroll
        for (int q = 0; q < 8; ++q) {
            jj[q] = __shfl(jA, e + q);
            cc[q] = __shfl(cA, e + q);
        }
#pragma unroll
        for (int q = 0; q < 8; ++q) uu[q] = HW2[jj[q] * 64 + lane];
#pragma unroll
        for (int q = 0; q < 8; q += 2) {
            a0 += cc[q] * __uint_as_float(uu[q] << 16);
            a1 += cc[q] * __uint_as_float(uu[q] & 0xFFFF0000u);
            b0 += cc[q + 1] * __uint_as_float(uu[q + 1] << 16);
            b1 += cc[q + 1] * __uint_as_float(uu[q + 1] & 0xFFFF0000u);
        }
    }
    for (; e < d0; ++e) {
        const int j0 = __shfl(jA, e);
        const float c0 = __shfl(cA, e);
        const uint u0 = HW2[j0 * 64 + lane];
        a0 += c0 * __uint_as_float(u0 << 16);
        a1 += c0 * __uint_as_float(u0 & 0xFFFF0000u);
    }
    if (deg > 64) {  // wave-uniform, essentially never taken
        int jB = 0;
        float cB = 0.f;
        if (64 + lane < deg) {
            jB = col[row * CAP + 64 + lane];
            const float x = si + t[jB];
            const float lr = x > 0.f ? x : 0.2f * x;
            cB = lr / fmaxf(sqrtf(norm2[jB]), 1e-12f);
        }
        const int d1 = deg - 64;
        for (e = 0; e < d1; ++e) {
            const int j0 = __shfl(jB, e);
            const float c0 = __shfl(cB, e);
            const uint u0 = HW2[j0 * 64 + lane];
            a0 += c0 * __uint_as_float(u0 << 16);
            a1 += c0 * __uint_as_float(u0 & 0xFFFF0000u);
        }
    }
    // lane l writes features (2l, 2l+1): coalesced float2
    float2 o;
    o.x = a0 + b0;
    o.y = a1 + b1;
    *(float2*)&out[row * 128 + 2 * lane] = o;
}

extern "C" void kernel_launch(void* const* d_in, const int* in_sizes, int n_in,
                              void* d_out, int out_size, void* d_ws, size_t ws_size,
                              hipStream_t stream) {
    const float* feat = (const float*)d_in[0];
    const float* Wm = (const float*)d_in[1];
    const float* a = (const float*)d_in[2];
    const int* edges = (const int*)d_in[3];
    const int* src = edges;
    const int* dst = edges + NE;
    float* out = (float*)d_out;

    // workspace layout (~10.3 MB)
    __hip_bfloat16* HWb = (__hip_bfloat16*)d_ws;  // NN*128 bf16 (2 MB)
    float* s = (float*)(HWb + NN * 128);          // NN
    float* t = s + NN;                            // NN
    float* norm2 = t + NN;                        // NN  \ adjacent: one memset
    int* cnt = (int*)(norm2 + NN);                // NN  /
    int* col = cnt + NN;                          // NN*CAP

    hipMemsetAsync(norm2, 0, 2 * NN * sizeof(float), stream);

    k_fused1<<<512 + NE / 256, 256, 0, stream>>>(feat, Wm, a, src, dst, HWb, s, t, cnt, col);
    k_dupnorm<<<NN / 4, 256, 0, stream>>>(cnt, col, s, t, norm2);
    k_spmm<<<NN / 4, 256, 0, stream>>>(cnt, col, s, t, norm2, HWb, out);
}